// Round 13
// baseline (258.855 us; speedup 1.0000x reference)
//
#include <hip/hip_runtime.h>
#include <hip/hip_bf16.h>

typedef __attribute__((ext_vector_type(8))) __bf16 bf16x8;
typedef __attribute__((ext_vector_type(4))) float f32x4;
typedef __attribute__((ext_vector_type(16))) float f32x16;
typedef __attribute__((ext_vector_type(4))) unsigned int u32x4;

#define DIM 1024
#define NHEADS 16
#define HDIM 64
#define BATCH 4
#define SEQ 2048
#define ROWS (BATCH * SEQ) /* 8192 */
#define SCL 0.18033688011112042f /* 0.125 * log2(e) */

__device__ inline unsigned short f2bf(float f) {
    __hip_bfloat16 h = __float2bfloat16(f);
    return *reinterpret_cast<unsigned short*>(&h);
}

// pack two floats to bf16x2 (RNE) -- v_cvt_pk_bf16_f32 on gfx950
__device__ inline unsigned int packbf2(float a, float b) {
    unsigned short ua = __builtin_bit_cast(unsigned short, (__bf16)a);
    unsigned short ub = __builtin_bit_cast(unsigned short, (__bf16)b);
    return (unsigned int)ua | ((unsigned int)ub << 16);
}

typedef const __attribute__((address_space(1))) unsigned int* gas_ptr;
typedef __attribute__((address_space(3))) unsigned int* las_ptr;
__device__ inline void gload16(const void* g, void* l) {
    __builtin_amdgcn_global_load_lds((gas_ptr)g, (las_ptr)l, 16, 0, 0);
}

// ---------------- fused prologue: cast x + transpose both weights (1 dispatch) -------------
__global__ __launch_bounds__(256) void prologue(const float* __restrict__ x,
                                                unsigned short* __restrict__ x_bf,
                                                const float* __restrict__ W_qkv,
                                                unsigned short* __restrict__ WqkvT,
                                                const float* __restrict__ W_proj,
                                                unsigned short* __restrict__ WprojT) {
    __shared__ float tile[32][33];
    const int blk = blockIdx.x;
    if (blk < 8192) {
        int i = blk * 256 + threadIdx.x;
        float4 v = ((const float4*)x)[i];
        ushort4 o;
        o.x = f2bf(v.x); o.y = f2bf(v.y); o.z = f2bf(v.z); o.w = f2bf(v.w);
        ((ushort4*)x_bf)[i] = o;
        return;
    }
    const float* in; unsigned short* outp; int C, srows, bx, byy; float scl;
    if (blk < 11264) {
        int t = blk - 8192;
        in = W_qkv; outp = WqkvT; C = 3 * DIM; srows = DIM; scl = SCL;
        bx = t % 96; byy = t / 96;
    } else {
        int t = blk - 11264;
        in = W_proj; outp = WprojT; C = DIM; srows = 0; scl = 1.f;
        bx = t & 31; byy = t >> 5;
    }
    const int R = DIM;
    int c0 = bx * 32, r0 = byy * 32;
    int tx = threadIdx.x & 31, ty = threadIdx.x >> 5; // 32 x 8
#pragma unroll
    for (int i = 0; i < 32; i += 8) {
        int r = r0 + ty + i, c = c0 + tx;
        tile[ty + i][tx] = in[(size_t)r * C + c];
    }
    __syncthreads();
#pragma unroll
    for (int i = 0; i < 32; i += 8) {
        int orow = c0 + ty + i, oc = r0 + tx;
        float v = tile[tx][ty + i];
        if (orow < srows) v *= scl;
        outp[(size_t)orow * R + oc] = f2bf(v);
    }
}

// =================== 256x128-tile 4-phase pipelined GEMM (K=1024), dual-epilogue ============
// Reshape of the R11-verified 8-phase template for exact CU residency:
//   qkv:  grid 24x32 = 768 blocks = 3.0 rounds (was 384 = 1.5 -> 75% util).
//   gemm2: grid 8x32 = 256 blocks = 1.0 round, pipelined (was 128^2 2-barrier ~590 TF).
// 8 waves (4M x 2N), per-wave 64x64, acc[4][4]. LDS 96 KiB = 2 buf x (A 32K + B 16K).
// Halves follow the wave decomposition: A-halfL = rows bit5==0 (what miL phases read,
// packed idx = (row>>6)*32 + (row&31)); B-halfL = cols bit5==0. Per tile u, 4 phases
// {ds_read; stage 1 half; barrier; setprio; 8 MFMA; setprio; barrier}; stages
// P1:AH(u+1)[2 loads] P2:BH(u+1)[1] P3:AL(u+2)[2] P4:BL(u+2)[1]; boundary vmcnt(3)
// leaves the newest AL+BL(u+2) in flight (never 0 mid-loop; u>=14 tail drains to 0).
// Swizzle: granule ^= (slot&7) via inverse-swizzled GLOBAL src + swizzled ds_read;
// packed read-row == fr (mod 8) so read swizzle stays ^(fr&7).
// Epilogue per wave (64 rows = ONE K/V pack unit, kg loop gone):
//   Cf!=null -> fp32 out + bias (gemm2); else Q->Cq (bias*SCL) / K->Kp / V->Vp.
// R12 audit (post container-flake): LDS write max 98304 exactly (fits); vmcnt invariant
// traced (tile u+1 fully landed at each boundary); all WAR hazards >=2 barriers apart;
// grid swizzle bijective (nwg%8==0); Kp/Vp extents exactly 16.8MB in-region.
__global__ __launch_bounds__(512, 2) void gemm_pipe(const unsigned short* __restrict__ A,   // [M][1024] bf16
                                                    const unsigned short* __restrict__ Bt,  // [N][1024] bf16
                                                    const float* __restrict__ bias,
                                                    unsigned short* __restrict__ Cq,
                                                    unsigned short* __restrict__ Kp,
                                                    unsigned short* __restrict__ Vp,
                                                    float* __restrict__ Cf, int N) {
    __shared__ __align__(16) char SMEM[98304];
    const int tid = threadIdx.x;
    const int lane = tid & 63, wave = tid >> 6;
    const int wr = wave >> 1, wc = wave & 1;      // 4M x 2N, per-wave 64x64
    const int fr = lane & 15, lh = lane >> 4;
    // XCD-chunk swizzle (nwg % 8 == 0 for both launches)
    const int nwg = gridDim.x * gridDim.y;
    const int gflat = blockIdx.y * gridDim.x + blockIdx.x;
    const int bidx = (gflat & 7) * (nwg >> 3) + (gflat >> 3);
    const int bx = bidx % gridDim.x, byy = bidx / gridDim.x;
    const int rowA = byy * 256, colB = bx * 128;

    // staging: slot s = wave*8 + lane/8 (A second load: +64); src granule = (lane&7)^(s&7)
    const int sA = wave * 8 + (lane >> 3);
    const int pr0 = (sA & 31) + (sA >> 5) * 64;        // packed slot -> global row/col offset
    const int glb = ((lane & 7) ^ (lane >> 3)) * 16;
    // ds_read: packed row = (wr|wc)*32 + (mi&1)*16 + fr -> row&7 == fr&7
    const int ga0 = ((lh) ^ (fr & 7)) * 16;            // ks=0 granule, swizzled
    const int ga1 = ((4 + lh) ^ (fr & 7)) * 16;        // ks=1 granule, swizzled
    const int aoff = (wr * 32 + fr) * 128;
    const int boff = (wc * 32 + fr) * 128;

    f32x4 acc[4][4] = {};

    auto stA = [&](int tb, int h, int tt) { // A half: 16 KB, 2 loads
        char* d = SMEM + tb * 49152 + h * 16384 + wave * 1024;
        const char* g0 = (const char*)A +
            (((size_t)(rowA + pr0 + h * 32)) * 1024 + (size_t)tt * 64) * 2 + glb;
        gload16(g0, d);
        gload16(g0 + (size_t)128 * 2048, d + 8192);
    };
    auto stB = [&](int tb, int h, int tt) { // B half: 8 KB, 1 load
        char* d = SMEM + tb * 49152 + 32768 + h * 8192 + wave * 1024;
        const char* g0 = (const char*)Bt +
            (((size_t)(colB + pr0 + h * 32)) * 1024 + (size_t)tt * 64) * 2 + glb;
        gload16(g0, d);
    };

    // prologue: tile0 all 4 halves + tile1 (AL, BL) = 9 loads; leave newest 3 in flight
    stA(0, 0, 0); stA(0, 1, 0); stB(0, 0, 0); stB(0, 1, 0);
    stA(1, 0, 1); stB(1, 0, 1);
    asm volatile("s_waitcnt vmcnt(3)" ::: "memory");
    __builtin_amdgcn_s_barrier();

    bf16x8 afq[2][2];
    for (int u = 0; u < 16; ++u) {
        const int cur = u & 1;
        const char* Al = SMEM + cur * 49152;
        const char* Bl = SMEM + cur * 49152 + 32768;
        // ---- phase 1: read A-halfL + B-halfL; MFMA (mi 0-1, ni 0-1); stage AH(u+1)
        {
            bf16x8 bfp[2][2];
#pragma unroll
            for (int i = 0; i < 2; i++) {
                afq[i][0] = *(const bf16x8*)(Al + aoff + i * 2048 + ga0);
                afq[i][1] = *(const bf16x8*)(Al + aoff + i * 2048 + ga1);
            }
#pragma unroll
            for (int j = 0; j < 2; j++) {
                bfp[j][0] = *(const bf16x8*)(Bl + boff + j * 2048 + ga0);
                bfp[j][1] = *(const bf16x8*)(Bl + boff + j * 2048 + ga1);
            }
            if (u + 1 < 16) stA(cur ^ 1, 1, u + 1);
            __builtin_amdgcn_s_barrier();
            __builtin_amdgcn_s_setprio(1);
#pragma unroll
            for (int i = 0; i < 2; i++)
#pragma unroll
                for (int j = 0; j < 2; j++) {
                    acc[i][j] = __builtin_amdgcn_mfma_f32_16x16x32_bf16(afq[i][0], bfp[j][0], acc[i][j], 0, 0, 0);
                    acc[i][j] = __builtin_amdgcn_mfma_f32_16x16x32_bf16(afq[i][1], bfp[j][1], acc[i][j], 0, 0, 0);
                }
            __builtin_amdgcn_s_setprio(0);
            __builtin_amdgcn_s_barrier();
        }
        // ---- phase 2: read B-halfH; MFMA (mi 0-1, ni 2-3); stage BH(u+1)
        {
            bf16x8 bfp[2][2];
#pragma unroll
            for (int j = 0; j < 2; j++) {
                bfp[j][0] = *(const bf16x8*)(Bl + 8192 + boff + j * 2048 + ga0);
                bfp[j][1] = *(const bf16x8*)(Bl + 8192 + boff + j * 2048 + ga1);
            }
            if (u + 1 < 16) stB(cur ^ 1, 1, u + 1);
            __builtin_amdgcn_s_barrier();
            __builtin_amdgcn_s_setprio(1);
#pragma unroll
            for (int i = 0; i < 2; i++)
#pragma unroll
                for (int j = 0; j < 2; j++) {
                    acc[i][2 + j] = __builtin_amdgcn_mfma_f32_16x16x32_bf16(afq[i][0], bfp[j][0], acc[i][2 + j], 0, 0, 0);
                    acc[i][2 + j] = __builtin_amdgcn_mfma_f32_16x16x32_bf16(afq[i][1], bfp[j][1], acc[i][2 + j], 0, 0, 0);
                }
            __builtin_amdgcn_s_setprio(0);
            __builtin_amdgcn_s_barrier();
        }
        // ---- phase 3: read A-halfH (overwrite afq) + B-halfL; MFMA (mi 2-3, ni 0-1); stage AL(u+2)
        {
            bf16x8 bfp[2][2];
#pragma unroll
            for (int i = 0; i < 2; i++) {
                afq[i][0] = *(const bf16x8*)(Al + 16384 + aoff + i * 2048 + ga0);
                afq[i][1] = *(const bf16x8*)(Al + 16384 + aoff + i * 2048 + ga1);
            }
#pragma unroll
            for (int j = 0; j < 2; j++) {
                bfp[j][0] = *(const bf16x8*)(Bl + boff + j * 2048 + ga0);
                bfp[j][1] = *(const bf16x8*)(Bl + boff + j * 2048 + ga1);
            }
            if (u + 2 < 16) stA(cur, 0, u + 2);
            __builtin_amdgcn_s_barrier();
            __builtin_amdgcn_s_setprio(1);
#pragma unroll
            for (int i = 0; i < 2; i++)
#pragma unroll
                for (int j = 0; j < 2; j++) {
                    acc[2 + i][j] = __builtin_amdgcn_mfma_f32_16x16x32_bf16(afq[i][0], bfp[j][0], acc[2 + i][j], 0, 0, 0);
                    acc[2 + i][j] = __builtin_amdgcn_mfma_f32_16x16x32_bf16(afq[i][1], bfp[j][1], acc[2 + i][j], 0, 0, 0);
                }
            __builtin_amdgcn_s_setprio(0);
            __builtin_amdgcn_s_barrier();
        }
        // ---- phase 4: read B-halfH; MFMA (mi 2-3, ni 2-3); stage BL(u+2); boundary vmcnt
        {
            bf16x8 bfp[2][2];
#pragma unroll
            for (int j = 0; j < 2; j++) {
                bfp[j][0] = *(const bf16x8*)(Bl + 8192 + boff + j * 2048 + ga0);
                bfp[j][1] = *(const bf16x8*)(Bl + 8192 + boff + j * 2048 + ga1);
            }
            if (u + 2 < 16) stB(cur, 0, u + 2);
            __builtin_amdgcn_s_barrier();
            __builtin_amdgcn_s_setprio(1);
#pragma unroll
            for (int i = 0; i < 2; i++)
#pragma unroll
                for (int j = 0; j < 2; j++) {
                    acc[2 + i][2 + j] = __builtin_amdgcn_mfma_f32_16x16x32_bf16(afq[i][0], bfp[j][0], acc[2 + i][2 + j], 0, 0, 0);
                    acc[2 + i][2 + j] = __builtin_amdgcn_mfma_f32_16x16x32_bf16(afq[i][1], bfp[j][1], acc[2 + i][2 + j], 0, 0, 0);
                }
            __builtin_amdgcn_s_setprio(0);
            if (u < 14) asm volatile("s_waitcnt vmcnt(3)" ::: "memory");
            else        asm volatile("s_waitcnt vmcnt(0)" ::: "memory");
            __builtin_amdgcn_s_barrier();
        }
    }

    // ---------------- epilogue ----------------
    const int cm = (lane >> 4) * 4, cn = lane & 15;
    const int gn0 = colB + wc * 64; // 64-wide, uniform class (boundaries are 128-multiples)
    const int gm0 = rowA + wr * 64;
    if (Cf) {
        for (int ni = 0; ni < 4; ni++) {
            int gn = gn0 + ni * 16 + cn;
            float bv = bias[gn];
            for (int mi = 0; mi < 4; mi++) {
#pragma unroll
                for (int r = 0; r < 4; r++)
                    Cf[(size_t)(gm0 + mi * 16 + cm + r) * N + gn] = acc[mi][ni][r] + bv;
            }
        }
    } else if (gn0 < 1024) {
        for (int ni = 0; ni < 4; ni++) {
            int gn = gn0 + ni * 16 + cn;
            float bv = bias[gn] * SCL;
            for (int mi = 0; mi < 4; mi++) {
#pragma unroll
                for (int r = 0; r < 4; r++)
                    Cq[(size_t)(gm0 + mi * 16 + cm + r) * 1024 + gn] = f2bf(acc[mi][ni][r] + bv);
            }
        }
    } else {
        // K or V: stage wave quadrant (64 keys x 64 cols) into wave-private LDS, repack
        const int mm = lane & 31, hh = lane >> 5;
        unsigned short* Lw = (unsigned short*)SMEM + wave * (64 * 72);
        for (int ni = 0; ni < 4; ni++) {
            float bv = bias[gn0 + ni * 16 + cn];
            for (int mi = 0; mi < 4; mi++) {
#pragma unroll
                for (int r = 0; r < 4; r++)
                    Lw[(mi * 16 + cm + r) * 72 + ni * 16 + cn] = f2bf(acc[mi][ni][r] + bv);
            }
        }
        __builtin_amdgcn_s_waitcnt(0); // own ds_writes visible to own ds_reads
        const int b = gm0 >> 11, s0g = gm0 & 2047;
        if (gn0 < 2048) {
            const int h = (gn0 - 1024) >> 6;
            const size_t by = (size_t)(b * 16 + h);
            const int kub = s0g >> 5;
#pragma unroll
            for (int f = 0; f < 8; f++) {
                int ktl = f >> 2, ks = f & 3;
                uint4 d = *(const uint4*)&Lw[(ktl * 32 + mm) * 72 + ks * 16 + hh * 8];
                *(uint4*)(Kp + ((by * 64 + kub + ktl) * 4 + ks) * 512 + lane * 8) = d;
            }
        } else {
            const int h = (gn0 - 2048) >> 6;
            const size_t by = (size_t)(b * 16 + h);
            const int vub = s0g >> 4;
#pragma unroll
            for (int f = 0; f < 8; f++) {
                int ksl = f >> 1, dt = f & 1;
                unsigned short tmp[8];
#pragma unroll
                for (int j = 0; j < 8; j++)
                    tmp[j] = Lw[(ksl * 16 + (j & 3) + 8 * (j >> 2) + 4 * hh) * 72 + dt * 32 + mm];
                *(uint4*)(Vp + ((by * 128 + vub + ksl) * 2 + dt) * 512 + lane * 8) =
                    *(uint4*)tmp;
            }
        }
    }
}

// ---- softmax + PV for one q-tile: exp2 of S^T C-frag, pack to bf16 (= PV A-frag), 2 MFMAs/dt
__device__ inline void softmax_pv(const f32x16& cfrag, const bf16x8 vf[2][2],
                                  f32x16& o0, f32x16& o1, float& psum) {
    unsigned int pk[8];
    float es[8];
#pragma unroll
    for (int p = 0; p < 8; p++) {
        float e0 = __builtin_amdgcn_exp2f(cfrag[2 * p]);
        float e1 = __builtin_amdgcn_exp2f(cfrag[2 * p + 1]);
        es[p] = e0 + e1;
        pk[p] = packbf2(e0, e1);
    }
    psum += ((es[0] + es[1]) + (es[2] + es[3])) + ((es[4] + es[5]) + (es[6] + es[7]));
    u32x4 lo = {pk[0], pk[1], pk[2], pk[3]};
    u32x4 hi = {pk[4], pk[5], pk[6], pk[7]};
    bf16x8 pa0 = __builtin_bit_cast(bf16x8, lo); // keys [ku*32, +16) permuted
    bf16x8 pa1 = __builtin_bit_cast(bf16x8, hi); // keys [ku*32+16, +16)
    o0 = __builtin_amdgcn_mfma_f32_32x32x16_bf16(pa0, vf[0][0], o0, 0, 0, 0);
    o1 = __builtin_amdgcn_mfma_f32_32x32x16_bf16(pa0, vf[0][1], o1, 0, 0, 0);
    o0 = __builtin_amdgcn_mfma_f32_32x32x16_bf16(pa1, vf[1][0], o0, 0, 0, 0);
    o1 = __builtin_amdgcn_mfma_f32_32x32x16_bf16(pa1, vf[1][1], o1, 0, 0, 0);
}

// ---- one 32-key step, qt-interleaved (R8-proven)
__device__ inline void attn_step(const bf16x8 kf[4], const bf16x8 vf[2][2],
                                 const bf16x8 qf[2][4], f32x16 oacc[2][2], float psum[2]) {
    f32x16 cf0 = {}, cf1 = {};
#pragma unroll
    for (int ks = 0; ks < 4; ks++)
        cf0 = __builtin_amdgcn_mfma_f32_32x32x16_bf16(kf[ks], qf[0][ks], cf0, 0, 0, 0);
#pragma unroll
    for (int ks = 0; ks < 4; ks++)
        cf1 = __builtin_amdgcn_mfma_f32_32x32x16_bf16(kf[ks], qf[1][ks], cf1, 0, 0, 0);
    softmax_pv(cf0, vf, oacc[0][0], oacc[0][1], psum[0]);
    softmax_pv(cf1, vf, oacc[1][0], oacc[1][1], psum[1]);
}

// ---------------- flash attention v11 (R8-proven, settled local optimum) -------------------
// 64q x 64d per wave at 2 waves/SIMD (~190 regs). Four structural variations regressed:
//   R2 cap128 -> spill 1.5GB; R4 cap170 -> spill 60MB; R7 32q tile -> intensity halved;
//   R9 MFMA-ones denominator -> +25% MFMA work > VALU savings.
// Do NOT shrink the tile / add min-waves hints / move the denominator to MFMA.
__global__ __launch_bounds__(256, 2) void attn_kernel(const unsigned short* __restrict__ Qb, // [8192][1024] prescaled
                                                      const unsigned short* __restrict__ Kp,
                                                      const unsigned short* __restrict__ Vp,
                                                      unsigned short* __restrict__ attnb) { // [8192][1024]
    __shared__ float Po[2][8 * 256]; // [qpair] partial O (one qt round at a time)
    __shared__ float Pl[2][128];     // [qpair] partial psum[2] per lane
    const int tid = threadIdx.x;
    const int lane = tid & 63, wave = tid >> 6;
    const int qpair = wave >> 1, ksplit = wave & 1;
    const int m31 = lane & 31, h = lane >> 5;
    const int gflat = blockIdx.y * gridDim.x + blockIdx.x; // [0, 1024)
    const int xcd = gflat & 7, slot = gflat >> 3;          // slot in [0, 128)
    const int by = xcd * 8 + (slot >> 4);                  // [0, 64): 8 panels/XCD
    const int qb = slot & 15;                              // [0, 16)
    const int b = by >> 4;
    const int bS = b * SEQ, hcol = (by & 15) * HDIM;
    const int q0 = qb * 128 + qpair * 64;

    bf16x8 qf[2][4];
#pragma unroll
    for (int qt = 0; qt < 2; qt++)
#pragma unroll
        for (int ks = 0; ks < 4; ks++)
            qf[qt][ks] = *(const bf16x8*)(Qb + (size_t)(bS + q0 + qt * 32 + m31) * 1024 +
                                          hcol + ks * 16 + h * 8);

    f32x16 oacc[2][2] = {}; // [qt][dt]: C row=q, col=d=dt*32+m31
    float psum[2] = {0.f, 0.f};

    const unsigned short* kbase = Kp + (size_t)by * 64 * 2048 + lane * 8;
    const unsigned short* vbase = Vp + (size_t)by * 128 * 1024 + lane * 8;

    const int ku0 = ksplit * 32; // each wave: 32 key-units of 32 keys
    bf16x8 kfa[4], kfb[4];
    {
        const unsigned short* kp = kbase + (size_t)ku0 * 2048;
#pragma unroll
        for (int ks = 0; ks < 4; ks++) kfa[ks] = *(const bf16x8*)(kp + ks * 512);
    }
    for (int ki = 0; ki < 32; ki += 2) {
        // even step: compute with kfa, prefetch K(ki+1) -> kfb
        {
            int ku = ku0 + ki;
            bf16x8 vf[2][2];
#pragma unroll
            for (int ks = 0; ks < 2; ks++) {
                const unsigned short* vp = vbase + ((size_t)ku * 2 + ks) * 1024;
                vf[ks][0] = *(const bf16x8*)(vp);
                vf[ks][1] = *(const bf16x8*)(vp + 512);
            }
            const unsigned short* kpn = kbase + (size_t)(ku + 1) * 2048;
#pragma unroll
            for (int ks = 0; ks < 4; ks++) kfb[ks] = *(const bf16x8*)(kpn + ks * 512);
            attn_step(kfa, vf, qf, oacc, psum);
        }
        // odd step: compute with kfb, prefetch K(ki+2) -> kfa (clamped, branchless)
        {
            int ku = ku0 + ki + 1;
            bf16x8 vf[2][2];
#pragma unroll
            for (int ks = 0; ks < 2; ks++) {
                const unsigned short* vp = vbase + ((size_t)ku * 2 + ks) * 1024;
                vf[ks][0] = *(const bf16x8*)(vp);
                vf[ks][1] = *(const bf16x8*)(vp + 512);
            }
            int kup = ku0 + ((ki + 2 < 32) ? (ki + 2) : 31); // last iter: redundant reload
            const unsigned short* kpn = kbase + (size_t)kup * 2048;
#pragma unroll
            for (int ks = 0; ks < 4; ks++) kfa[ks] = *(const bf16x8*)(kpn + ks * 512);
            attn_step(kfb, vf, qf, oacc, psum);
        }
    }

    // two-round combine (qt=0 then qt=1): ksplit=1 parks partials, ksplit=0 sums.
#pragma unroll
    for (int qt = 0; qt < 2; qt++) {
        if (ksplit == 1) {
#pragma unroll
            for (int dt = 0; dt < 2; dt++)
#pragma unroll
                for (int c = 0; c < 4; c++) {
                    f32x4 v = {oacc[qt][dt][c * 4 + 0], oacc[qt][dt][c * 4 + 1],
                               oacc[qt][dt][c * 4 + 2], oacc[qt][dt][c * 4 + 3]};
                    *(f32x4*)&Po[qpair][(dt * 4 + c) * 256 + lane * 4] = v;
                }
            if (qt == 0)
                *(float2*)&Pl[qpair][lane * 2] = make_float2(psum[0], psum[1]);
        }
        __syncthreads();
        if (ksplit == 0) {
#pragma unroll
            for (int dt = 0; dt < 2; dt++)
#pragma unroll
                for (int c = 0; c < 4; c++) {
                    f32x4 v = *(const f32x4*)&Po[qpair][(dt * 4 + c) * 256 + lane * 4];
#pragma unroll
                    for (int j = 0; j < 4; j++) oacc[qt][dt][c * 4 + j] += v[j];
                }
            if (qt == 0) {
                float2 pl = *(const float2*)&Pl[qpair][lane * 2];
                psum[0] += pl.x; psum[1] += pl.y;
            }
        }
        if (qt == 0) __syncthreads(); // Po reused by round 2
    }

    if (ksplit == 0) {
        // epilogue: l[q] = psum(h=0)+psum(h=1); C rows: row=(r&3)+8*(r>>2)+4h
#pragma unroll
        for (int qt = 0; qt < 2; qt++) {
            float lt = psum[qt] + __shfl_xor(psum[qt], 32, 64);
            float rl = 1.f / lt; // valid on lanes where m31 == q
#pragma unroll
            for (int r = 0; r < 16; r++) {
                int row = (r & 3) + 8 * (r >> 2) + 4 * h;
                float rlr = __shfl(rl, row, 64);
                size_t orow = (size_t)(bS + q0 + qt * 32 + row) * 1024 + hcol;
                attnb[orow + m31]      = f2bf(oacc[qt][0][r] * rlr);
                attnb[orow + 32 + m31] = f2bf(oacc[qt][1][r] * rlr);
            }
        }
    }
}

extern "C" void kernel_launch(void* const* d_in, const int* in_sizes, int n_in,
                              void* d_out, int out_size, void* d_ws, size_t ws_size,
                              hipStream_t stream) {
    const float* x      = (const float*)d_in[0]; // [4,2048,1024]
    const float* W_qkv  = (const float*)d_in[1]; // [1024,3072]
    const float* b_qkv  = (const float*)d_in[2]; // [3072]
    const float* W_proj = (const float*)d_in[3]; // [1024,1024]
    const float* b_proj = (const float*)d_in[4]; // [1024]
    float* out = (float*)d_out;                  // [4,2048,1024]

    char* ws = (char*)d_ws;
    // lifetimes: x_bf,WqkvT die after gemm1 (Kp/Vp written DURING gemm1 -> own regions);
    // attnb aliases x_bf. Peak 75.5 MiB.
    unsigned short* x_bf   = (unsigned short*)(ws);                // [0, 16.8M)
    unsigned short* WqkvT  = (unsigned short*)(ws + 16777216);     // [16.8M, 23.1M)
    unsigned short* Qb     = (unsigned short*)(ws + 23068672);     // [23.1M, 39.8M)
    unsigned short* Kp     = (unsigned short*)(ws + 39845888);     // [39.8M, 56.6M)
    unsigned short* Vp     = (unsigned short*)(ws + 56623104);     // [56.6M, 73.4M)
    unsigned short* WprojT = (unsigned short*)(ws + 73400320);     // [73.4M, 75.5M)
    unsigned short* attnb  = (unsigned short*)(ws);                // reuses x_bf

    // 1) fused prologue: cast x + transpose W_qkv (Q cols pre-scaled) + transpose W_proj
    prologue<<<12288, 256, 0, stream>>>(x, x_bf, W_qkv, WqkvT, W_proj, WprojT);

    // 2) qkv: 256x128-tile pipelined GEMM -> Qb + Kp/Vp; 768 blocks = exactly 3 rounds
    gemm_pipe<<<dim3(24, 32), 512, 0, stream>>>(x_bf, WqkvT, b_qkv, Qb, Kp, Vp,
                                                nullptr, 3 * DIM);

    // 3) attention (x_bf dead; attnb reuses it): 128 q/block, KV split across wave pairs
    attn_kernel<<<dim3(SEQ / 128, BATCH * NHEADS), 256, 0, stream>>>(Qb, Kp, Vp, attnb);

    // 4) out = attn @ W_proj + b_proj (fp32): same pipelined kernel; 256 blocks = 1 round
    gemm_pipe<<<dim3(8, 32), 512, 0, stream>>>(attnb, WprojT, b_proj, nullptr, nullptr,
                                               nullptr, out, DIM);
}